// Round 2
// baseline (1215.424 us; speedup 1.0000x reference)
//
#include <hip/hip_runtime.h>

#define NN 4096
#define CH 256
#define NHEAD 8
#define DHEAD 32
#define RS 136   // per-wave P-tile row stride in bf16 (272 B: keeps 16B alignment for b128 DS ops)

typedef __attribute__((ext_vector_type(8))) short bf8_t;   // 8 bf16 values (4 VGPRs)
typedef __attribute__((ext_vector_type(4))) float f4_t;    // MFMA accumulator / native float4

__device__ __forceinline__ unsigned short f2bf(float f) {
    unsigned int u = __float_as_uint(f);
    u += 0x7FFFu + ((u >> 16) & 1u);       // round-to-nearest-even
    return (unsigned short)(u >> 16);
}

// ---------------- Kernel A: QKV projection, bf16 cast, layout shuffle ----------------
// Q/K stored shuffled: Qbf[i][h*32+d] = Q[i][d*8+h]  (contiguous MFMA A/B frags)
// V stored natural:    Vbf[j][c]      = V[j][c]      (c=d*8+h; contiguous PV B frags)
// Also zeroes the attn_out accumulator slice for this row block.
__global__ __launch_bounds__(256) void qkv_kernel(
    const float* __restrict__ X,
    const float* __restrict__ Wq, const float* __restrict__ bq,
    const float* __restrict__ Wk, const float* __restrict__ bk,
    const float* __restrict__ Wv, const float* __restrict__ bv,
    unsigned short* __restrict__ Qbf, unsigned short* __restrict__ Kbf,
    unsigned short* __restrict__ Vbf, float* __restrict__ ao)
{
    __shared__ __align__(16) float xs[16 * 256];
    const int c = threadIdx.x;
    const int i0 = blockIdx.x * 16;
    for (int r = 0; r < 16; ++r) xs[r * 256 + c] = X[(size_t)(i0 + r) * 256 + c];
    ao[(size_t)i0 * 32 + c] = 0.f;            // zero attn_out accumulator (512 floats/block)
    ao[(size_t)i0 * 32 + 256 + c] = 0.f;
    __syncthreads();

    float aq[16], ak[16], av[16];
#pragma unroll
    for (int r = 0; r < 16; ++r) { aq[r] = 0.f; ak[r] = 0.f; av[r] = 0.f; }

    for (int k = 0; k < 256; k += 4) {
        float wq0 = Wq[(k + 0) * 256 + c], wq1 = Wq[(k + 1) * 256 + c];
        float wq2 = Wq[(k + 2) * 256 + c], wq3 = Wq[(k + 3) * 256 + c];
        float wk0 = Wk[(k + 0) * 256 + c], wk1 = Wk[(k + 1) * 256 + c];
        float wk2 = Wk[(k + 2) * 256 + c], wk3 = Wk[(k + 3) * 256 + c];
        float wv0 = Wv[(k + 0) * 256 + c], wv1 = Wv[(k + 1) * 256 + c];
        float wv2 = Wv[(k + 2) * 256 + c], wv3 = Wv[(k + 3) * 256 + c];
#pragma unroll
        for (int r = 0; r < 16; ++r) {
            const float4 x = *(const float4*)&xs[r * 256 + k];
            aq[r] += x.x * wq0 + x.y * wq1 + x.z * wq2 + x.w * wq3;
            ak[r] += x.x * wk0 + x.y * wk1 + x.z * wk2 + x.w * wk3;
            av[r] += x.x * wv0 + x.y * wv1 + x.z * wv2 + x.w * wv3;
        }
    }

    const int cs = (c & 7) * 32 + (c >> 3);   // shuffled column: h*32 + d
    const float bqv = bq[c], bkv = bk[c], bvv = bv[c];
#pragma unroll
    for (int r = 0; r < 16; ++r) {
        const size_t row = (size_t)(i0 + r) * 256;
        Qbf[row + cs] = f2bf(aq[r] + bqv);
        Kbf[row + cs] = f2bf(ak[r] + bkv);
        Vbf[row + c]  = f2bf(av[r] + bvv);
    }
}

// ---------------- Kernel B: fused scores + softmax(head axis) + attn write + PV ----------------
// v2: per-wave independent pipeline — NO __syncthreads in the main loop.
//   * each wave owns one 16-row i-tile x 256-col j-slice (16 chunks of 16 j)
//   * wave computes ALL 8 head MFMAs for its 16x16 chunk -> softmax over h is register-local
//   * rel loaded straight to registers (prefetched 1 chunk ahead) and added post-MFMA (C=0)
//   * P transpose (rows-held -> A-frag) via per-wave private LDS tile; within-wave DS is
//     in-order, so a single s_waitcnt lgkmcnt(0) replaces all barriers
//   * V frags hoisted above softmax so L2 latency hides under exp/pack
__global__ __launch_bounds__(256) void attn_kernel(
    const unsigned short* __restrict__ Qbf, const unsigned short* __restrict__ Kbf,
    const unsigned short* __restrict__ Vbf, const float* __restrict__ rel,
    float* __restrict__ attn_g, float* __restrict__ ao)
{
    __shared__ __align__(16) unsigned short at_s[4][16 * RS];   // per-wave P bf16 tiles (17.4 KB)

    const int tid = threadIdx.x;
    const int w = tid >> 6, lane = tid & 63;
    const int quad = lane >> 4, l16 = lane & 15;
    const int i0 = blockIdx.x * 16;
    const int jw0 = blockIdx.y * 1024 + w * 256;   // this wave's j range: 16 chunks of 16

    // persistent Q frags: A[m=l16][k=quad*8+e] = Q[i0+l16][head h, d=quad*8+e]
    bf8_t qf[8];
#pragma unroll
    for (int h = 0; h < 8; ++h)
        qf[h] = *(const bf8_t*)(Qbf + (size_t)(i0 + l16) * 256 + h * 32 + quad * 8);

    f4_t pv0 = {0.f, 0.f, 0.f, 0.f};
    f4_t pv1 = {0.f, 0.f, 0.f, 0.f};
    unsigned short* ats = at_s[w];

    // rel addend: lane (quad,l16) covers rows i=quad*4+r, col j=jb+l16, all 8 h contiguous
    const float* relb = rel + (size_t)(i0 + quad * 4) * (NN * 8) + (size_t)l16 * 8;

    // prefetch chunk 0's rel (8 floats per r = h0..7)
    f4_t rga[4], rgb[4];
#pragma unroll
    for (int r = 0; r < 4; ++r) {
        const float* gp = relb + (size_t)r * (NN * 8) + (size_t)jw0 * 8;
        rga[r] = *(const f4_t*)gp;
        rgb[r] = *((const f4_t*)gp + 1);
    }

    for (int t = 0; t < 16; ++t) {
        const int jb = jw0 + t * 16;

        // --- scores: d[h] = q_h * k_h^T (C = 0; rel folded in at softmax, fp32) ---
        const unsigned short* kb = Kbf + (size_t)(jb + l16) * 256 + quad * 8;
        const f4_t z4 = {0.f, 0.f, 0.f, 0.f};
        f4_t d[8];
#pragma unroll
        for (int h = 0; h < 8; ++h) {
            const bf8_t kf = *(const bf8_t*)(kb + h * 32);
            d[h] = __builtin_amdgcn_mfma_f32_16x16x32_bf16(qf[h], kf, z4, 0, 0, 0);
        }

        // --- V frags issued early (L2-resident; latency hides under softmax) ---
        // B[k=quad*8+e][n=l16] = V[jb+s*4+quad][channel (dhalf*16+l16)*8+e]
        bf8_t v0s[4], v1s[4];
        const unsigned short* vb = Vbf + (size_t)jb * 256;
#pragma unroll
        for (int s = 0; s < 4; ++s) {
            const unsigned short* vp = vb + (size_t)(s * 4 + quad) * 256 + l16 * 8;
            v0s[s] = *(const bf8_t*)vp;
            v1s[s] = *(const bf8_t*)(vp + 128);
        }

        // --- softmax over the 8 heads (register-local) + attn store + bf16 pack to LDS ---
        // no max-subtraction: |scores| < ~10 -> exp safe in fp32
#pragma unroll
        for (int r = 0; r < 4; ++r) {
            float e0 = __expf(d[0][r] + rga[r].x);
            float e1 = __expf(d[1][r] + rga[r].y);
            float e2 = __expf(d[2][r] + rga[r].z);
            float e3 = __expf(d[3][r] + rga[r].w);
            float e4 = __expf(d[4][r] + rgb[r].x);
            float e5 = __expf(d[5][r] + rgb[r].y);
            float e6 = __expf(d[6][r] + rgb[r].z);
            float e7 = __expf(d[7][r] + rgb[r].w);
            const float inv = 1.0f / (e0 + e1 + e2 + e3 + e4 + e5 + e6 + e7);
            e0 *= inv; e1 *= inv; e2 *= inv; e3 *= inv;
            e4 *= inv; e5 *= inv; e6 *= inv; e7 *= inv;
            float* gp = attn_g + ((size_t)(i0 + quad * 4 + r) * NN + (size_t)(jb + l16)) * 8;
            const f4_t o0 = {e0, e1, e2, e3};
            const f4_t o1 = {e4, e5, e6, e7};
            __builtin_nontemporal_store(o0, (f4_t*)gp);
            __builtin_nontemporal_store(o1, (f4_t*)gp + 1);
            const unsigned int p0 = (unsigned int)f2bf(e0) | ((unsigned int)f2bf(e1) << 16);
            const unsigned int p1 = (unsigned int)f2bf(e2) | ((unsigned int)f2bf(e3) << 16);
            const unsigned int p2 = (unsigned int)f2bf(e4) | ((unsigned int)f2bf(e5) << 16);
            const unsigned int p3 = (unsigned int)f2bf(e6) | ((unsigned int)f2bf(e7) << 16);
            *(uint4*)&ats[(quad * 4 + r) * RS + l16 * 8] = make_uint4(p0, p1, p2, p3);
        }

        // --- prefetch next chunk's rel (rg regs dead after softmax; full chunk to cover HBM) ---
        if (t != 15) {
#pragma unroll
            for (int r = 0; r < 4; ++r) {
                const float* gp = relb + (size_t)r * (NN * 8) + (size_t)(jb + 16) * 8;
                rga[r] = *(const f4_t*)gp;
                rgb[r] = *((const f4_t*)gp + 1);
            }
        }

        // within-wave DS ordering: all lanes' P writes visible before A-frag reads
        asm volatile("s_waitcnt lgkmcnt(0)" ::: "memory");

        // --- PV: all 4 k-slices of this chunk (A[m=l16][k=quad*8+e] = P[i=l16][j=s*4+quad][h=e]) ---
#pragma unroll
        for (int s = 0; s < 4; ++s) {
            const bf8_t af = *(const bf8_t*)&ats[l16 * RS + (s * 4 + quad) * 8];
            pv0 = __builtin_amdgcn_mfma_f32_16x16x32_bf16(af, v0s[s], pv0, 0, 0, 0);
            pv1 = __builtin_amdgcn_mfma_f32_16x16x32_bf16(af, v1s[s], pv1, 0, 0, 0);
        }
    }

    // epilogue: accumulate wave-partial attn_out (C layout: row=quad*4+r, col=lane&15)
#pragma unroll
    for (int r = 0; r < 4; ++r) {
        const size_t row = (size_t)(i0 + quad * 4 + r) * 32;
        atomicAdd(&ao[row + l16], pv0[r]);
        atomicAdd(&ao[row + 16 + l16], pv1[r]);
    }
}

// ---------------- Kernel C: MLP  out = relu(ao@W1+b1)@W2 + b2 ----------------
__global__ __launch_bounds__(256) void mlp_kernel(
    const float* __restrict__ ao, const float* __restrict__ W1, const float* __restrict__ b1,
    const float* __restrict__ W2, const float* __restrict__ b2, float* __restrict__ out)
{
    __shared__ __align__(16) float aos[16 * 32];
    __shared__ __align__(16) float hid[16 * 256];
    const int c = threadIdx.x;
    const int i0 = blockIdx.x * 16;
    aos[c]       = ao[(size_t)i0 * 32 + c];
    aos[c + 256] = ao[(size_t)i0 * 32 + 256 + c];
    __syncthreads();

    float w1r[32];
#pragma unroll
    for (int d = 0; d < 32; ++d) w1r[d] = W1[d * 256 + c];
    const float b1v = b1[c];
    for (int r = 0; r < 16; ++r) {
        float h = b1v;
#pragma unroll
        for (int d = 0; d < 32; ++d) h += aos[r * 32 + d] * w1r[d];
        hid[r * 256 + c] = fmaxf(h, 0.f);
    }
    __syncthreads();

    float acc[16];
    const float b2v = b2[c];
#pragma unroll
    for (int r = 0; r < 16; ++r) acc[r] = b2v;
    for (int k = 0; k < 256; k += 4) {
        const float w20 = W2[(k + 0) * 256 + c], w21 = W2[(k + 1) * 256 + c];
        const float w22 = W2[(k + 2) * 256 + c], w23 = W2[(k + 3) * 256 + c];
#pragma unroll
        for (int r = 0; r < 16; ++r) {
            const float4 hh = *(const float4*)&hid[r * 256 + k];
            acc[r] += hh.x * w20 + hh.y * w21 + hh.z * w22 + hh.w * w23;
        }
    }
#pragma unroll
    for (int r = 0; r < 16; ++r) out[(size_t)(i0 + r) * 256 + c] = acc[r];
}

extern "C" void kernel_launch(void* const* d_in, const int* in_sizes, int n_in,
                              void* d_out, int out_size, void* d_ws, size_t ws_size,
                              hipStream_t stream)
{
    const float* X   = (const float*)d_in[0];
    const float* rel = (const float*)d_in[1];
    const float* Wq  = (const float*)d_in[3];
    const float* bq  = (const float*)d_in[4];
    const float* Wk  = (const float*)d_in[5];
    const float* bk  = (const float*)d_in[6];
    const float* Wv  = (const float*)d_in[7];
    const float* bv  = (const float*)d_in[8];
    const float* W1  = (const float*)d_in[9];
    const float* b1  = (const float*)d_in[10];
    const float* W2  = (const float*)d_in[11];
    const float* b2  = (const float*)d_in[12];

    float* out    = (float*)d_out;
    float* attn_g = out + (size_t)NN * CH;      // outputs: (output[N,256], attn[N,N,8])

    // workspace: Qbf 2MB | Kbf 2MB | Vbf 2MB | attn_out 512KB  (6.8 MB total)
    unsigned short* Qbf = (unsigned short*)d_ws;
    unsigned short* Kbf = Qbf + (size_t)NN * CH;
    unsigned short* Vbf = Kbf + (size_t)NN * CH;
    float* ao = (float*)(Vbf + (size_t)NN * CH);

    qkv_kernel<<<dim3(256), dim3(256), 0, stream>>>(X, Wq, bq, Wk, bk, Wv, bv, Qbf, Kbf, Vbf, ao);
    attn_kernel<<<dim3(256, 4), dim3(256), 0, stream>>>(Qbf, Kbf, Vbf, rel, attn_g, ao);
    mlp_kernel<<<dim3(256), dim3(256), 0, stream>>>(ao, W1, b1, W2, b2, out);
}

// Round 3
// 1051.265 us; speedup vs baseline: 1.1562x; 1.1562x over previous
//
#include <hip/hip_runtime.h>

#define NN 4096
#define CH 256
#define NHEAD 8
#define DHEAD 32
#define RS 136    // at_s row stride in bf16 (272 B)
#define SCS 132   // sc_s row stride in floats (padded: breaks 16-way bank conflict)
#define NCH 32    // j-chunks per block (512 j / 16)

typedef __attribute__((ext_vector_type(8))) short bf8_t;   // 8 bf16 values (4 VGPRs)
typedef __attribute__((ext_vector_type(4))) float f4_t;    // MFMA accumulator / native float4

__device__ __forceinline__ unsigned short f2bf(float f) {
    unsigned int u = __float_as_uint(f);
    u += 0x7FFFu + ((u >> 16) & 1u);       // round-to-nearest-even
    return (unsigned short)(u >> 16);
}

// raw barrier: lgkmcnt(0) ensures this thread's DS writes/reads are complete before the
// barrier; sched_barrier(0) pins post-barrier LDS ops from hoisting into the gap.
// Crucially does NOT drain vmcnt -> global prefetches stay in flight across phases.
#define BARRIER() do {                                          \
    asm volatile("s_waitcnt lgkmcnt(0)" ::: "memory");          \
    __builtin_amdgcn_s_barrier();                               \
    __builtin_amdgcn_sched_barrier(0);                          \
} while (0)

// ---------------- Kernel A: QKV projection, bf16 cast, layout shuffle ----------------
__global__ __launch_bounds__(256) void qkv_kernel(
    const float* __restrict__ X,
    const float* __restrict__ Wq, const float* __restrict__ bq,
    const float* __restrict__ Wk, const float* __restrict__ bk,
    const float* __restrict__ Wv, const float* __restrict__ bv,
    unsigned short* __restrict__ Qbf, unsigned short* __restrict__ Kbf,
    unsigned short* __restrict__ Vbf, float* __restrict__ ao)
{
    __shared__ __align__(16) float xs[16 * 256];
    const int c = threadIdx.x;
    const int i0 = blockIdx.x * 16;
    for (int r = 0; r < 16; ++r) xs[r * 256 + c] = X[(size_t)(i0 + r) * 256 + c];
    ao[(size_t)i0 * 32 + c] = 0.f;            // zero attn_out accumulator (512 floats/block)
    ao[(size_t)i0 * 32 + 256 + c] = 0.f;
    __syncthreads();

    float aq[16], ak[16], av[16];
#pragma unroll
    for (int r = 0; r < 16; ++r) { aq[r] = 0.f; ak[r] = 0.f; av[r] = 0.f; }

    for (int k = 0; k < 256; k += 4) {
        float wq0 = Wq[(k + 0) * 256 + c], wq1 = Wq[(k + 1) * 256 + c];
        float wq2 = Wq[(k + 2) * 256 + c], wq3 = Wq[(k + 3) * 256 + c];
        float wk0 = Wk[(k + 0) * 256 + c], wk1 = Wk[(k + 1) * 256 + c];
        float wk2 = Wk[(k + 2) * 256 + c], wk3 = Wk[(k + 3) * 256 + c];
        float wv0 = Wv[(k + 0) * 256 + c], wv1 = Wv[(k + 1) * 256 + c];
        float wv2 = Wv[(k + 2) * 256 + c], wv3 = Wv[(k + 3) * 256 + c];
#pragma unroll
        for (int r = 0; r < 16; ++r) {
            const float4 x = *(const float4*)&xs[r * 256 + k];
            aq[r] += x.x * wq0 + x.y * wq1 + x.z * wq2 + x.w * wq3;
            ak[r] += x.x * wk0 + x.y * wk1 + x.z * wk2 + x.w * wk3;
            av[r] += x.x * wv0 + x.y * wv1 + x.z * wv2 + x.w * wv3;
        }
    }

    const int cs = (c & 7) * 32 + (c >> 3);   // shuffled column: h*32 + d
    const float bqv = bq[c], bkv = bk[c], bvv = bv[c];
#pragma unroll
    for (int r = 0; r < 16; ++r) {
        const size_t row = (size_t)(i0 + r) * 256;
        Qbf[row + cs] = f2bf(aq[r] + bqv);
        Kbf[row + cs] = f2bf(ak[r] + bkv);
        Vbf[row + c]  = f2bf(av[r] + bvv);
    }
}

// ---------------- Kernel B: fused scores + softmax(head axis) + attn write + PV ----------------
// v3: Round-0 cooperative structure + deep prefetch + raw barriers.
//   * rel prefetched 2 chunks deep in registers (8 floats/thread/chunk); by the time its
//     counted vmcnt fires the load is ~2 chunks (>HBM latency) old -> no stall
//   * load ISSUE ORDER chosen so no consumer's vmcnt wait forces a young rel load:
//     per chunk t: [V(t)] [rel(t+2)] ... [K(t+1)]  (vmcnt queue completes oldest-first)
//   * raw s_barrier + lgkmcnt(0) (no compiler vmcnt(0) drain at barriers)
//   * sc_s stride 132 floats: score C-preload/writeback conflicts 16-way -> 8-way
//   * grid y-split 8 (2048 blocks) for ~5 co-resident blocks/CU of latency hiding
__global__ __launch_bounds__(256) void attn_kernel(
    const unsigned short* __restrict__ Qbf, const unsigned short* __restrict__ Kbf,
    const unsigned short* __restrict__ Vbf, const float* __restrict__ rel,
    float* __restrict__ attn_g, float* __restrict__ ao)
{
    __shared__ __align__(16) float sc_s[16 * SCS];             // rel -> scores fp32 (8.25 KB)
    __shared__ __align__(16) unsigned short at_s[16 * RS];     // attn bf16 (4.25 KB)

    const int tid = threadIdx.x;
    const int w = tid >> 6, lane = tid & 63;
    const int quad = lane >> 4, l16 = lane & 15;
    const int i0 = blockIdx.x * 16;
    const int jbase = blockIdx.y * (NCH * 16);

    // persistent Q frags: A[m=l16][k=quad*8+e] for heads 2w, 2w+1
    bf8_t qf0 = *(const bf8_t*)(Qbf + (size_t)(i0 + l16) * 256 + (2 * w + 0) * 32 + quad * 8);
    bf8_t qf1 = *(const bf8_t*)(Qbf + (size_t)(i0 + l16) * 256 + (2 * w + 1) * 32 + quad * 8);

    f4_t pv0 = {0.f, 0.f, 0.f, 0.f};
    f4_t pv1 = {0.f, 0.f, 0.f, 0.f};

    const int so = tid * 8, sri = so >> 7, src = so & 127;   // rel staging map: 8 floats/thread
    const int jlw = w * 4 + quad;                            // PV k-slice j within chunk
    const int smi = tid >> 4, smj = tid & 15;                // softmax map (i, jl)

    const float* relp = rel + (size_t)(i0 + sri) * (NN * 8) + src;

    // prologue: rel(0), rel(1), K(0) — queue order matches first-consumption order
    f4_t ra0, rb0, ra1, rb1;
    { const float* g = relp + (size_t)(jbase +  0) * 8; ra0 = *(const f4_t*)g; rb0 = *((const f4_t*)g + 1); }
    { const float* g = relp + (size_t)(jbase + 16) * 8; ra1 = *(const f4_t*)g; rb1 = *((const f4_t*)g + 1); }
    bf8_t kf0 = *(const bf8_t*)(Kbf + (size_t)(jbase + l16) * 256 + (2 * w + 0) * 32 + quad * 8);
    bf8_t kf1 = *(const bf8_t*)(Kbf + (size_t)(jbase + l16) * 256 + (2 * w + 1) * 32 + quad * 8);

#define CHUNK(JC, RA, RB) {                                                                     \
    const int jb = jbase + (JC) * 16;                                                           \
    /* V(t): issued first so PV's vmcnt wait never touches rel(t+2) */                          \
    const unsigned short* vb = Vbf + (size_t)(jb + jlw) * 256 + l16 * 8;                        \
    const bf8_t v0f = *(const bf8_t*)vb;                                                        \
    const bf8_t v1f = *(const bf8_t*)(vb + 128);                                                \
    /* stage rel(t) from regs (compiler waits counted vmcnt for RA/RB: ~2 chunks old) */        \
    *(f4_t*)&sc_s[sri * SCS + src]     = RA;                                                    \
    *(f4_t*)&sc_s[sri * SCS + src + 4] = RB;                                                    \
    /* prefetch rel(t+2) into the regs just freed */                                            \
    if ((JC) + 2 < NCH) {                                                                       \
        const float* g = relp + (size_t)(jb + 32) * 8;                                          \
        RA = *(const f4_t*)g; RB = *((const f4_t*)g + 1);                                       \
    }                                                                                           \
    BARRIER();                                                                                  \
    /* scores: D = q_h k_h^T + rel (C preloaded from LDS), written back in place */             \
    {                                                                                           \
        f4_t cf0, cf1;                                                                          \
        _Pragma("unroll")                                                                       \
        for (int r = 0; r < 4; ++r) cf0[r] = sc_s[(quad * 4 + r) * SCS + l16 * 8 + 2 * w];      \
        _Pragma("unroll")                                                                       \
        for (int r = 0; r < 4; ++r) cf1[r] = sc_s[(quad * 4 + r) * SCS + l16 * 8 + 2 * w + 1];  \
        const f4_t d0 = __builtin_amdgcn_mfma_f32_16x16x32_bf16(qf0, kf0, cf0, 0, 0, 0);        \
        const f4_t d1 = __builtin_amdgcn_mfma_f32_16x16x32_bf16(qf1, kf1, cf1, 0, 0, 0);        \
        _Pragma("unroll")                                                                       \
        for (int r = 0; r < 4; ++r) sc_s[(quad * 4 + r) * SCS + l16 * 8 + 2 * w] = d0[r];       \
        _Pragma("unroll")                                                                       \
        for (int r = 0; r < 4; ++r) sc_s[(quad * 4 + r) * SCS + l16 * 8 + 2 * w + 1] = d1[r];   \
    }                                                                                           \
    BARRIER();                                                                                  \
    /* K(t+1): issued here -> consumed after next B1, ~400 cy of cover for L2 latency */        \
    if ((JC) + 1 < NCH) {                                                                       \
        kf0 = *(const bf8_t*)(Kbf + (size_t)(jb + 16 + l16) * 256 + (2 * w + 0) * 32 + quad * 8); \
        kf1 = *(const bf8_t*)(Kbf + (size_t)(jb + 16 + l16) * 256 + (2 * w + 1) * 32 + quad * 8); \
    }                                                                                           \
    /* softmax over 8 heads + attn store + bf16 pack to LDS */                                  \
    {                                                                                           \
        const float* sp = &sc_s[smi * SCS + smj * 8];                                           \
        const f4_t s0 = *(const f4_t*)sp;                                                       \
        const f4_t s1 = *((const f4_t*)sp + 1);                                                 \
        float e0 = __expf(s0[0]), e1 = __expf(s0[1]), e2 = __expf(s0[2]), e3 = __expf(s0[3]);   \
        float e4 = __expf(s1[0]), e5 = __expf(s1[1]), e6 = __expf(s1[2]), e7 = __expf(s1[3]);   \
        const float inv = 1.0f / (e0 + e1 + e2 + e3 + e4 + e5 + e6 + e7);                       \
        e0 *= inv; e1 *= inv; e2 *= inv; e3 *= inv;                                             \
        e4 *= inv; e5 *= inv; e6 *= inv; e7 *= inv;                                             \
        float* gp = attn_g + ((size_t)(i0 + smi) * NN + (size_t)(jb + smj)) * 8;                \
        const f4_t o0 = {e0, e1, e2, e3};                                                       \
        const f4_t o1 = {e4, e5, e6, e7};                                                       \
        *(f4_t*)gp       = o0;                                                                  \
        *((f4_t*)gp + 1) = o1;                                                                  \
        const unsigned int p0 = (unsigned int)f2bf(e0) | ((unsigned int)f2bf(e1) << 16);        \
        const unsigned int p1 = (unsigned int)f2bf(e2) | ((unsigned int)f2bf(e3) << 16);        \
        const unsigned int p2 = (unsigned int)f2bf(e4) | ((unsigned int)f2bf(e5) << 16);        \
        const unsigned int p3 = (unsigned int)f2bf(e6) | ((unsigned int)f2bf(e7) << 16);        \
        *(uint4*)&at_s[smi * RS + smj * 8] = make_uint4(p0, p1, p2, p3);                        \
    }                                                                                           \
    BARRIER();                                                                                  \
    /* PV: wave sums its (jl, h) k-slice; A[m=l16][k=quad*8+e] = P[l16][jlw][e] */              \
    {                                                                                           \
        const bf8_t af = *(const bf8_t*)&at_s[l16 * RS + jlw * 8];                              \
        pv0 = __builtin_amdgcn_mfma_f32_16x16x32_bf16(af, v0f, pv0, 0, 0, 0);                   \
        pv1 = __builtin_amdgcn_mfma_f32_16x16x32_bf16(af, v1f, pv1, 0, 0, 0);                   \
    }                                                                                           \
}

    for (int jc = 0; jc < NCH; jc += 2) {
        CHUNK(jc,     ra0, rb0);
        CHUNK(jc + 1, ra1, rb1);
    }
#undef CHUNK

    // epilogue: accumulate wave-partial attn_out (C layout: row=quad*4+r, col=lane&15)
#pragma unroll
    for (int r = 0; r < 4; ++r) {
        const size_t row = (size_t)(i0 + quad * 4 + r) * 32;
        atomicAdd(&ao[row + l16], pv0[r]);
        atomicAdd(&ao[row + 16 + l16], pv1[r]);
    }
}

// ---------------- Kernel C: MLP  out = relu(ao@W1+b1)@W2 + b2 ----------------
__global__ __launch_bounds__(256) void mlp_kernel(
    const float* __restrict__ ao, const float* __restrict__ W1, const float* __restrict__ b1,
    const float* __restrict__ W2, const float* __restrict__ b2, float* __restrict__ out)
{
    __shared__ __align__(16) float aos[16 * 32];
    __shared__ __align__(16) float hid[16 * 256];
    const int c = threadIdx.x;
    const int i0 = blockIdx.x * 16;
    aos[c]       = ao[(size_t)i0 * 32 + c];
    aos[c + 256] = ao[(size_t)i0 * 32 + 256 + c];
    __syncthreads();

    float w1r[32];
#pragma unroll
    for (int d = 0; d < 32; ++d) w1r[d] = W1[d * 256 + c];
    const float b1v = b1[c];
    for (int r = 0; r < 16; ++r) {
        float h = b1v;
#pragma unroll
        for (int d = 0; d < 32; ++d) h += aos[r * 32 + d] * w1r[d];
        hid[r * 256 + c] = fmaxf(h, 0.f);
    }
    __syncthreads();

    float acc[16];
    const float b2v = b2[c];
#pragma unroll
    for (int r = 0; r < 16; ++r) acc[r] = b2v;
    for (int k = 0; k < 256; k += 4) {
        const float w20 = W2[(k + 0) * 256 + c], w21 = W2[(k + 1) * 256 + c];
        const float w22 = W2[(k + 2) * 256 + c], w23 = W2[(k + 3) * 256 + c];
#pragma unroll
        for (int r = 0; r < 16; ++r) {
            const float4 hh = *(const float4*)&hid[r * 256 + k];
            acc[r] += hh.x * w20 + hh.y * w21 + hh.z * w22 + hh.w * w23;
        }
    }
#pragma unroll
    for (int r = 0; r < 16; ++r) out[(size_t)(i0 + r) * 256 + c] = acc[r];
}

extern "C" void kernel_launch(void* const* d_in, const int* in_sizes, int n_in,
                              void* d_out, int out_size, void* d_ws, size_t ws_size,
                              hipStream_t stream)
{
    const float* X   = (const float*)d_in[0];
    const float* rel = (const float*)d_in[1];
    const float* Wq  = (const float*)d_in[3];
    const float* bq  = (const float*)d_in[4];
    const float* Wk  = (const float*)d_in[5];
    const float* bk  = (const float*)d_in[6];
    const float* Wv  = (const float*)d_in[7];
    const float* bv  = (const float*)d_in[8];
    const float* W1  = (const float*)d_in[9];
    const float* b1  = (const float*)d_in[10];
    const float* W2  = (const float*)d_in[11];
    const float* b2  = (const float*)d_in[12];

    float* out    = (float*)d_out;
    float* attn_g = out + (size_t)NN * CH;      // outputs: (output[N,256], attn[N,N,8])

    // workspace: Qbf 2MB | Kbf 2MB | Vbf 2MB | attn_out 512KB  (6.8 MB total)
    unsigned short* Qbf = (unsigned short*)d_ws;
    unsigned short* Kbf = Qbf + (size_t)NN * CH;
    unsigned short* Vbf = Kbf + (size_t)NN * CH;
    float* ao = (float*)(Vbf + (size_t)NN * CH);

    qkv_kernel<<<dim3(256), dim3(256), 0, stream>>>(X, Wq, bq, Wk, bk, Wv, bv, Qbf, Kbf, Vbf, ao);
    attn_kernel<<<dim3(256, 8), dim3(256), 0, stream>>>(Qbf, Kbf, Vbf, rel, attn_g, ao);
    mlp_kernel<<<dim3(256), dim3(256), 0, stream>>>(ao, W1, b1, W2, b2, out);
}